// Round 7
// baseline (77.043 us; speedup 1.0000x reference)
//
#include <hip/hip_runtime.h>
#include <hip/hip_fp16.h>
#include <math.h>

#define NB 512
#define TT 26
#define LL 64
#define HH 32
#define WW 128

typedef unsigned long long ull;

__device__ __forceinline__ void nts(float* p, float v) {
  __builtin_nontemporal_store(v, p);
}

__device__ __forceinline__ float wave_sum(float v) {
#pragma unroll
  for (int o = 32; o > 0; o >>= 1) v += __shfl_xor(v, o, 64);
  return v;
}

template<int CTRL, int RM>
__device__ __forceinline__ float dpp_add(float x) {
  int y = __builtin_amdgcn_update_dpp(0, __float_as_int(x), CTRL, RM, 0xf, true);
  return x + __int_as_float(y);
}
// sum across 64 lanes via DPP (VALU pipe only); result valid in lane 63
__device__ __forceinline__ float wave_red63(float x) {
  x = dpp_add<0x111, 0xf>(x);   // row_shr:1
  x = dpp_add<0x112, 0xf>(x);   // row_shr:2
  x = dpp_add<0x114, 0xf>(x);   // row_shr:4
  x = dpp_add<0x118, 0xf>(x);   // row_shr:8
  x = dpp_add<0x142, 0xa>(x);   // row_bcast15 -> rows 1,3
  x = dpp_add<0x143, 0xc>(x);   // row_bcast31 -> rows 2,3; lane63 = total
  return x;
}

__device__ __forceinline__ void unpack_acc(unsigned hpair, unsigned c0, unsigned c1,
                                           int t, float& msum, float& isum) {
  __half2 h2 = *reinterpret_cast<__half2*>(&hpair);
  float2 f = __half22float2(h2);
  msum += f.x + f.y;
  isum += ((c0 >> t) & 1) ? f.x : 0.f;
  isum += ((c1 >> t) & 1) ? f.y : 0.f;
}

// ---------------- Phase 1: per-sample attention work ----------------
__global__ __launch_bounds__(128) void k_phase1(
    const float* __restrict__ seq, const int* __restrict__ length,
    const float* __restrict__ alpha_p, float* __restrict__ wsA,
    ull* __restrict__ amid, unsigned int* __restrict__ alow,
    float* __restrict__ irr_part)
{
  int b = blockIdx.x;
  int tid = threadIdx.x;
  __shared__ float att[LL * TT];
  __shared__ float wpart[2];
  const float* sb = seq + (size_t)b * (LL * TT);
  for (int i = tid; i < LL * TT; i += 128) att[i] = sb[i];
  __syncthreads();
  int n = length[b] - 1;
  float alpha = alpha_p[0];

  int w = tid;
  int k = w >> 1;
  int i0, i1; float c0, c1;
  if ((w & 1) == 0) {
    if (k == 0) { i0 = 0; i1 = 0; c0 = 1.f; c1 = 0.f; }
    else        { i0 = k - 1; i1 = k; c0 = 0.25f; c1 = 0.75f; }
  } else {
    if (k == 63) { i0 = 63; i1 = 63; c0 = 1.f; c1 = 0.f; }
    else         { i0 = k; i1 = k + 1; c0 = 0.75f; c1 = 0.25f; }
  }
  float S = 0.f, S2 = 0.f, A = 0.f;
  for (int t = 0; t < n; ++t) {
    float v = c0 * att[i0 * TT + t] + c1 * att[i1 * TT + t];
    float s = v * v;
    S += s; S2 += s * s;
    A += 1.f / (1.f + __expf(-70.f * (v - 0.1f)));
  }
  wsA[b * WW + w] = A;

  float c = S * S - S2;
  c = wave_sum(c);
  if ((tid & 63) == 0) wpart[tid >> 6] = c;
  __syncthreads();
  if (tid == 0) irr_part[b] = 0.5f * (wpart[0] + wpart[1]) / (float)n;

  if (tid < 64) {
    int x = tid;                       // middle: identity resize, 64 cols
    for (int t = 0; t < TT; ++t) {
      bool pred = (t < n) && (att[x * TT + t] > alpha);
      ull m = __ballot(pred);
      if (x == 0) amid[b * TT + t] = m;
    }
  } else {
    int x = tid - 64;                  // low: pairwise mean, 32 cols
    for (int t = 0; t < TT; ++t) {
      bool pred = (x < 32) && (t < n) &&
                  (0.5f * (att[(2 * x) * TT + t] + att[(2 * x + 1) * TT + t]) > alpha);
      ull m = __ballot(pred);
      if (x == 0) alow[b * TT + t] = (unsigned int)m;
    }
  }
}

// ---------------- Phase 2: seg CE + correct CE + fore bitmask ----------------
__global__ __launch_bounds__(256) void k_phase2(
    const float* __restrict__ masks, const float* __restrict__ bf,
    const float* __restrict__ wsA, float* __restrict__ seg_part,
    float* __restrict__ cor_part, ull* __restrict__ fmsk)
{
  int bid = blockIdx.x;
  int b = bid >> 2, q = bid & 3;
  int tid = threadIdx.x;
  int lane = tid & 63, wv = tid >> 6;
  const float* mb = masks + (size_t)b * 4096 + q * 1024;
  const float* fb = bf + (size_t)b * 8192 + q * 1024;

  float A = wsA[b * WW + (tid & 127)];
  float cs = fminf(fmaxf(A, 0.f), 1.f);
  float ce_fore = log1pf(__expf(1.f - 2.f * cs));

  float seg_acc = 0.f, cor_acc = 0.f;
  for (int k = 0; k < 4; ++k) {
    int px = k * 256 + tid;
    float m = mb[px];
    float b0 = fb[px];
    float b1 = fb[4096 + px];
    float mx = fmaxf(b0, b1);
    float e0 = __expf(b0 - mx), e1 = __expf(b1 - mx);
    float inv = 1.f / (e0 + e1);
    float p0 = e0 * inv, p1 = e1 * inv;
    float pm = fmaxf(p0, p1);
    float lse = pm + log1pf(__expf(-fabsf(p1 - p0)));
    seg_acc += lse - ((m > 0.5f) ? p1 : p0);
    bool fore = b1 > b0;
    cor_acc += fore ? ce_fore : 0.313261687518222834f;
    ull fbm = __ballot(fore);
    if (lane == 0) fmsk[(size_t)b * 64 + q * 16 + k * 4 + wv] = fbm;
  }
  seg_acc = wave_sum(seg_acc);
  cor_acc = wave_sum(cor_acc);
  __shared__ float ps[4], pc[4];
  if (lane == 0) { ps[wv] = seg_acc; pc[wv] = cor_acc; }
  __syncthreads();
  if (tid == 0) {
    seg_part[bid] = ps[0] + ps[1] + ps[2] + ps[3];
    cor_part[bid] = pc[0] + pc[1] + pc[2] + pc[3];
  }
}

// ---------------- Phase 3 (fused): low blocks [0,256), mid blocks [256,1280) ----------------
// 512 threads, 1 px/thread; dice reductions via f16 LDS transpose; NT output stores
__global__ __launch_bounds__(512) void k_chars(
    const float* __restrict__ cm, const float* __restrict__ cl,
    const ull* __restrict__ fmsk, const ull* __restrict__ amid,
    const unsigned int* __restrict__ alow,
    float* __restrict__ out_mask, float* __restrict__ out_smid,
    float* __restrict__ out_slow,
    float* __restrict__ celm_part, float* __restrict__ cell_part,
    float* __restrict__ inter_midP, float* __restrict__ m1s_midP, float* __restrict__ m2s_midP,
    float* __restrict__ inter_low, float* __restrict__ m1s_low, float* __restrict__ m2s_low)
{
  int blk = blockIdx.x;
  int tid = threadIdx.x;
  int lane = tid & 63, wv = tid >> 6;
  __shared__ __align__(16) char smem[34432];

  if (blk >= 256) {
    // ============ mid branch: 2 blocks per b (half h = 8 rows), 1 px/thread ============
    int bm_ = blk - 256;
    int b = bm_ >> 1, h = bm_ & 1;
    __half*   m1h     = (__half*)(smem);                    // [26][520]
    unsigned* cbkA    = (unsigned*)(smem + 27040);          // [512]
    float (*part_in)[16] = (float(*)[16])(smem + 29088);    // [26][16]
    float (*part_m1)[16] = (float(*)[16])(smem + 30752);    // [26][16]
    ull*      s_bits  = (ull*)(smem + 32416);               // [26]
    unsigned* s_cols  = (unsigned*)(smem + 32624);          // [64]
    ull*      s_fmw   = (ull*)(smem + 32880);               // [32]
    ull*      s_fmrow = (ull*)(smem + 33136);               // [8]
    float*    s_ce    = (float*)(smem + 33200);             // [8]

    if (tid < TT) s_bits[tid] = amid[b * TT + tid];
    if (tid >= 32 && tid < 64) s_fmw[tid - 32] = fmsk[(size_t)b * 64 + h * 32 + (tid - 32)];
    __syncthreads();
    if (tid < 64) {
      unsigned cb = 0;
#pragma unroll
      for (int t = 0; t < TT; ++t) cb |= (unsigned)((s_bits[t] >> tid) & 1ULL) << t;
      s_cols[tid] = cb;
    }
    __syncthreads();

    int ly = tid >> 6;               // local row 0..7 (== wv)
    int x = tid & 63;
    int px = h * 512 + tid;
    int word = x >> 5;
    int p = (x & 31) * 2;
    ull r0 = s_fmw[4 * ly + word];
    ull r1 = s_fmw[4 * ly + 2 + word];
    int cnt = (int)((r0 >> p) & 1) + (int)((r0 >> (p + 1)) & 1)
            + (int)((r1 >> p) & 1) + (int)((r1 >> (p + 1)) & 1);
    bool fm = cnt >= 2;
    unsigned cbk = s_cols[x];
    int lab = (fm && cbk) ? __ffs((int)cbk) : 0;
    if (!fm) cbk = 0;
    ull bmv = __ballot(fm);
    if (lane == 0) s_fmrow[wv] = bmv;
    cbkA[tid] = cbk;

    const float* base = cm + (size_t)b * 27 * 1024 + px;
    float v[27];
    float xl = 0.f, s0 = 0.f;
#pragma unroll
    for (int c = 0; c < 27; ++c) {
      float r = base[(size_t)c * 1024];
      xl = (c == lab) ? r : xl;
      r = __expf(r);
      v[c] = r;
      s0 += r;
    }
    float inv0 = 1.f / s0;
    float ce_part = __logf(s0) - xl;

    float* os = out_smid + (size_t)b * 26 * 1024 + px;
#pragma unroll
    for (int t = 0; t < TT; ++t) {
      float m1 = v[t + 1] * inv0;
      nts(os + (size_t)t * 1024, m1);
      m1h[t * 520 + tid] = __float2half(m1);
    }
    float rce = wave_red63(ce_part);
    if (lane == 63) s_ce[wv] = rce;
    __syncthreads();

    // phase B: (t, chunk-of-32-px) per thread
    {
      int t = tid >> 4, c = tid & 15;
      if (t < TT) {
        const uint4* pm = (const uint4*)(m1h + t * 520 + c * 32);
        const uint4* pc = (const uint4*)(cbkA + c * 32);
        float isum = 0.f, msum = 0.f;
#pragma unroll
        for (int q = 0; q < 4; ++q) {
          uint4 mh = pm[q];
          uint4 cA = pc[2 * q];
          uint4 cB = pc[2 * q + 1];
          unpack_acc(mh.x, cA.x, cA.y, t, msum, isum);
          unpack_acc(mh.y, cA.z, cA.w, t, msum, isum);
          unpack_acc(mh.z, cB.x, cB.y, t, msum, isum);
          unpack_acc(mh.w, cB.z, cB.w, t, msum, isum);
        }
        part_in[t][c] = isum;
        part_m1[t][c] = msum;
      }
    }
    __syncthreads();
    if (tid < TT) {
      float m2v = 0.f;
#pragma unroll
      for (int r = 0; r < 8; ++r) m2v += (float)__popcll(s_fmrow[r] & s_bits[tid]);
      float si = 0.f, sm = 0.f;
#pragma unroll
      for (int c = 0; c < 16; ++c) { si += part_in[tid][c]; sm += part_m1[tid][c]; }
      int o = (2 * b + h) * TT + tid;
      m2s_midP[o] = m2v;
      inter_midP[o] = si;
      m1s_midP[o] = sm;
    }
    if (tid == TT) {
      float c8 = 0.f;
#pragma unroll
      for (int w = 0; w < 8; ++w) c8 += s_ce[w];
      celm_part[2 * b + h] = c8;
    }
  } else {
    // ============ low branch: 2 b per block, 1 px/thread ============
    __half*   m1hL    = (__half*)(smem);                    // [2][26][264]
    unsigned* cbkL    = (unsigned*)(smem + 27456);          // [2][256]
    float (*partL_in)[8] = (float(*)[8])(smem + 29504);     // [2*26][8]
    float (*partL_m1)[8] = (float(*)[8])(smem + 31168);     // [2*26][8]
    unsigned* l_bits  = (unsigned*)(smem + 32832);          // [2][26]
    unsigned* colsL   = (unsigned*)(smem + 33040);          // [2][32]
    ull*      fmwL    = (ull*)(smem + 33296);               // [2][64]
    unsigned* fmrow32 = (unsigned*)(smem + 34320);          // [2][8]
    float*    ceL     = (float*)(smem + 34384);             // [8]

    int bI = tid >> 8;                // 0..1
    int bb = blk * 2 + bI;
    int px = tid & 255;
    int y = px >> 5, x = px & 31;
    if (tid < 2 * TT) {
      int bi = tid / TT, t = tid - bi * TT;
      l_bits[bi * TT + t] = alow[(blk * 2 + bi) * TT + t];
    }
    if (tid >= 128 && tid < 256) {
      int j = tid - 128;
      fmwL[j] = fmsk[(size_t)(blk * 2 + (j >> 6)) * 64 + (j & 63)];
    }
    __syncthreads();
    if (tid < 64) {
      int bi = tid >> 5, xc = tid & 31;
      unsigned cb = 0;
#pragma unroll
      for (int t = 0; t < TT; ++t) cb |= ((l_bits[bi * TT + t] >> xc) & 1u) << t;
      colsL[bi * 32 + xc] = cb;
    }
    __syncthreads();

    int wb = 4 * x + 1;
    int word = wb >> 6;
    int p = wb & 63;
    ull r0 = fmwL[bI * 64 + (4 * y + 1) * 2 + word];
    ull r1 = fmwL[bI * 64 + (4 * y + 2) * 2 + word];
    int cnt = (int)((r0 >> p) & 1) + (int)((r0 >> (p + 1)) & 1)
            + (int)((r1 >> p) & 1) + (int)((r1 >> (p + 1)) & 1);
    bool fm = cnt >= 2;
    unsigned cbk = colsL[bI * 32 + x];
    int lab = (fm && cbk) ? __ffs((int)cbk) : 0;
    if (!fm) cbk = 0;
    ull bmv = __ballot(fm);
    if (lane == 0) {
      int wq = wv & 3;
      fmrow32[bI * 8 + 2 * wq] = (unsigned)bmv;
      fmrow32[bI * 8 + 2 * wq + 1] = (unsigned)(bmv >> 32);
    }
    cbkL[bI * 256 + px] = cbk;

    const float* base = cl + (size_t)bb * 27 * 256 + px;
    float v[27];
    float xl = 0.f, s0 = 0.f;
#pragma unroll
    for (int c = 0; c < 27; ++c) {
      float r = base[(size_t)c * 256];
      xl = (c == lab) ? r : xl;
      r = __expf(r);
      v[c] = r;
      s0 += r;
    }
    float inv0 = 1.f / s0;
    float ce_part = __logf(s0) - xl;

    float* om  = out_mask + (size_t)bb * 27 * 256 + px;
    float* osf = out_slow + (size_t)bb * 26 * 256 + px;
    nts(om, fm ? 0.f : 1.f);
#pragma unroll
    for (int t = 0; t < TT; ++t) {
      float m1 = v[t + 1] * inv0;
      nts(osf + (size_t)t * 256, m1);
      nts(om + (size_t)(t + 1) * 256, ((cbk >> t) & 1) ? 1.f : 0.f);
      m1hL[(bI * TT + t) * 264 + px] = __float2half(m1);
    }
    float rce = wave_red63(ce_part);
    if (lane == 63) ceL[wv] = rce;
    __syncthreads();

    // phase B: (t, chunk-of-32-px) per thread within each b
    {
      int r = tid & 255;
      int t = r >> 3, c = r & 7;
      if (t < TT) {
        const uint4* pm = (const uint4*)(m1hL + (bI * TT + t) * 264 + c * 32);
        const uint4* pc = (const uint4*)(cbkL + bI * 256 + c * 32);
        float isum = 0.f, msum = 0.f;
#pragma unroll
        for (int q = 0; q < 4; ++q) {
          uint4 mh = pm[q];
          uint4 cA = pc[2 * q];
          uint4 cB = pc[2 * q + 1];
          unpack_acc(mh.x, cA.x, cA.y, t, msum, isum);
          unpack_acc(mh.y, cA.z, cA.w, t, msum, isum);
          unpack_acc(mh.z, cB.x, cB.y, t, msum, isum);
          unpack_acc(mh.w, cB.z, cB.w, t, msum, isum);
        }
        partL_in[bI * TT + t][c] = isum;
        partL_m1[bI * TT + t][c] = msum;
      }
    }
    __syncthreads();
    if (tid < 2 * TT) {
      int bi = tid / TT, t = tid - bi * TT;
      float m2v = 0.f;
#pragma unroll
      for (int yy = 0; yy < 8; ++yy) m2v += (float)__popc(fmrow32[bi * 8 + yy] & l_bits[bi * TT + t]);
      float si = 0.f, sm = 0.f;
#pragma unroll
      for (int c = 0; c < 8; ++c) { si += partL_in[bi * TT + t][c]; sm += partL_m1[bi * TT + t][c]; }
      int o = (blk * 2 + bi) * TT + t;
      m2s_low[o] = m2v;
      inter_low[o] = si;
      m1s_low[o] = sm;
    }
    if (tid >= 2 * TT && tid < 2 * TT + 2) {
      int bi = tid - 2 * TT;
      cell_part[blk * 2 + bi] = ceL[bi * 4] + ceL[bi * 4 + 1] + ceL[bi * 4 + 2] + ceL[bi * 4 + 3];
    }
  }
}

// ---------------- Phase 4: finalize scalars ----------------
__global__ __launch_bounds__(1024) void k_final(
    const float* __restrict__ seg_part, const float* __restrict__ cor_part,
    const float* __restrict__ irr_part, const float* __restrict__ celm_part,
    const float* __restrict__ cell_part,
    const float* __restrict__ inter_midP, const float* __restrict__ m1s_midP,
    const float* __restrict__ m2s_midP,
    const float* __restrict__ inter_low, const float* __restrict__ m1s_low,
    const float* __restrict__ m2s_low,
    const int* __restrict__ length, const int* __restrict__ iter_p,
    float* __restrict__ out)
{
  int tid = threadIdx.x;
  float dm = 0.f, dl = 0.f;
  for (int i = tid; i < NB * TT; i += 1024) {
    int b = i / TT, t = i - b * TT;
    int n = length[b] - 1;
    if (t < n) {
      float inv_n = 1.f / (float)n;
      int o0 = (2 * b) * TT + t, o1 = (2 * b + 1) * TT + t;
      float im = inter_midP[o0] + inter_midP[o1];
      float mm = m1s_midP[o0] + m1s_midP[o1];
      float m2 = m2s_midP[o0] + m2s_midP[o1];
      dm += (1.f - (2.f * im + 1.f) / (mm + m2 + 1.f)) * inv_n;
      dl += (1.f - (2.f * inter_low[i] + 1.f) / (m1s_low[i] + m2s_low[i] + 1.f)) * inv_n;
    }
  }
  float ss = 0.f, sel = 0.f, ssel = 0.f;
  float irr = 0.f, cell = 0.f;
  for (int b = tid; b < NB; b += 1024) {
    float v = seg_part[4 * b] + seg_part[4 * b + 1] + seg_part[4 * b + 2] + seg_part[4 * b + 3];
    ss += v;
    float val = v * (1.f / 4096.f);
    if (val < 1.f) { sel += 1.f; ssel += val; }
    irr += irr_part[b]; cell += cell_part[b];
  }
  float cor = 0.f, celm = 0.f;
  for (int i = tid; i < 4 * NB; i += 1024) cor += cor_part[i];
  for (int i = tid; i < 2 * NB; i += 1024) celm += celm_part[i];

  dm = wave_sum(dm); dl = wave_sum(dl); ss = wave_sum(ss);
  sel = wave_sum(sel); ssel = wave_sum(ssel);
  irr = wave_sum(irr); celm = wave_sum(celm); cell = wave_sum(cell);
  cor = wave_sum(cor);
  __shared__ float red[9][16];
  int wv = tid >> 6;
  if ((tid & 63) == 0) {
    red[0][wv] = dm; red[1][wv] = dl; red[2][wv] = ss; red[3][wv] = sel;
    red[4][wv] = ssel; red[5][wv] = irr; red[6][wv] = celm; red[7][wv] = cell;
    red[8][wv] = cor;
  }
  __syncthreads();
  if (tid == 0) {
    float a[9];
#pragma unroll
    for (int j = 0; j < 9; ++j) {
      float s = 0.f;
      for (int i = 0; i < 16; ++i) s += red[j][i];
      a[j] = s;
    }
    float pred = (iter_p[0] > 20000) ? (a[4] / fmaxf(a[3], 1.f)) : (a[2] / 2097152.f);
    out[0] = pred;
    out[1] = a[8] / 2097152.f + a[5];
    out[2] = a[7] / 131072.f + a[1] / 512.f;   // loss_low
    out[3] = a[6] / 524288.f + a[0] / 512.f;   // loss_middle
  }
}

extern "C" void kernel_launch(void* const* d_in, const int* in_sizes, int n_in,
                              void* d_out, int out_size, void* d_ws, size_t ws_size,
                              hipStream_t stream) {
  (void)in_sizes; (void)n_in; (void)out_size; (void)ws_size;
  const float* masks  = (const float*)d_in[0];
  const float* bf     = (const float*)d_in[1];
  const float* seq    = (const float*)d_in[2];
  const float* cmid   = (const float*)d_in[3];
  const float* clow   = (const float*)d_in[4];
  const int*   length = (const int*)d_in[5];
  const int*   iter   = (const int*)d_in[6];
  const float* alpha  = (const float*)d_in[7];
  float* out = (float*)d_out;

  char* ws = (char*)d_ws;
  // all scratch fully rewritten every launch -> no memset
  float* seg_part   = (float*)(ws + 0);        // 2048 f32
  float* cor_part   = (float*)(ws + 8192);     // 2048 f32
  float* irr_part   = (float*)(ws + 16384);    // 512 f32
  float* celm_part  = (float*)(ws + 18432);    // 1024 f32
  float* cell_part  = (float*)(ws + 22528);    // 512 f32
  float* inter_midP = (float*)(ws + 24576);    // 1024*26 f32 = 106496 B
  float* m1s_midP   = (float*)(ws + 131072);
  float* m2s_midP   = (float*)(ws + 237568);
  ull*          amid = (ull*)(ws + 344064);          // 512*26 u64
  unsigned int* alow = (unsigned int*)(ws + 450560); // 512*26 u32
  ull*          fmsk = (ull*)(ws + 503808);          // 512*64 u64
  float*        wsA  = (float*)(ws + 765952);        // 512*128 f32 (dead after phase2)
  // low dice arrays alias wsA region (written in k_chars after wsA's last read)
  float* inter_low = (float*)(ws + 765952);
  float* m1s_low   = (float*)(ws + 819200);
  float* m2s_low   = (float*)(ws + 872448);          // ends 925696

  k_phase1<<<NB, 128, 0, stream>>>(seq, length, alpha, wsA, amid, alow, irr_part);
  k_phase2<<<NB * 4, 256, 0, stream>>>(masks, bf, wsA, seg_part, cor_part, fmsk);

  float* out_mask = out + 4;
  float* out_smid = out + 4 + 3538944;
  float* out_slow = out + 4 + 3538944 + 13631488;

  k_chars<<<256 + 2 * NB, 512, 0, stream>>>(cmid, clow, fmsk, amid, alow,
                                            out_mask, out_smid, out_slow,
                                            celm_part, cell_part,
                                            inter_midP, m1s_midP, m2s_midP,
                                            inter_low, m1s_low, m2s_low);
  k_final<<<1, 1024, 0, stream>>>(seg_part, cor_part, irr_part, celm_part, cell_part,
                                  inter_midP, m1s_midP, m2s_midP,
                                  inter_low, m1s_low, m2s_low, length, iter, out);
}

// Round 8
// 65.627 us; speedup vs baseline: 1.1740x; 1.1740x over previous
//
#include <hip/hip_runtime.h>
#include <math.h>

#define NB 512
#define TT 26
#define LL 64
#define HH 32
#define WW 128

typedef unsigned long long ull;

__device__ __forceinline__ float wave_sum(float v) {
#pragma unroll
  for (int o = 32; o > 0; o >>= 1) v += __shfl_xor(v, o, 64);
  return v;
}

template<int CTRL, int RM>
__device__ __forceinline__ float dpp_add(float x) {
  int y = __builtin_amdgcn_update_dpp(0, __float_as_int(x), CTRL, RM, 0xf, true);
  return x + __int_as_float(y);
}
// sum across 64 lanes via DPP (VALU pipe only); result valid in lane 63
__device__ __forceinline__ float wave_red63(float x) {
  x = dpp_add<0x111, 0xf>(x);   // row_shr:1
  x = dpp_add<0x112, 0xf>(x);   // row_shr:2
  x = dpp_add<0x114, 0xf>(x);   // row_shr:4
  x = dpp_add<0x118, 0xf>(x);   // row_shr:8
  x = dpp_add<0x142, 0xa>(x);   // row_bcast15 -> rows 1,3
  x = dpp_add<0x143, 0xc>(x);   // row_bcast31 -> rows 2,3; lane63 = total
  return x;
}

// ================= Mega kernel: one block per sample b, 1024 threads =================
__global__ __launch_bounds__(1024) void k_mega(
    const float* __restrict__ masks, const float* __restrict__ bf,
    const float* __restrict__ seq, const float* __restrict__ cm,
    const float* __restrict__ cl, const int* __restrict__ length,
    const float* __restrict__ alpha_p,
    float* __restrict__ out_mask, float* __restrict__ out_smid,
    float* __restrict__ out_slow,
    float* __restrict__ seg_part, float* __restrict__ cor_part,
    float* __restrict__ irr_part, float* __restrict__ celm_part,
    float* __restrict__ cell_part,
    float* __restrict__ inter_mid, float* __restrict__ m1s_mid, float* __restrict__ m2s_mid,
    float* __restrict__ inter_low, float* __restrict__ m1s_low, float* __restrict__ m2s_low)
{
  int b = blockIdx.x;
  int tid = threadIdx.x;
  int lane = tid & 63, wv = tid >> 6;

  __shared__ float att[LL * TT];          // [l][t]
  __shared__ float wsA_lds[WW];
  __shared__ ull s_bits[TT];              // amid bitmasks (64 cols)
  __shared__ unsigned s_alow[TT];         // alow bitmasks (32 cols)
  __shared__ unsigned s_cols_mid[64];
  __shared__ unsigned s_cols_low[32];
  __shared__ ull fmsk_lds[64];            // fore mask, 32 rows x 2 words
  __shared__ ull s_fmrow[16];             // mid fm row masks
  __shared__ unsigned fmrow32[8];         // low fm row masks
  __shared__ float s_red_in[16][TT], s_red_m1[16][TT];
  __shared__ float s_ce[16];
  __shared__ float ps[16], pc[16];
  __shared__ float wpart[2];

  int n = length[b] - 1;
  float alpha = alpha_p[0];

  // ---- load attention [64][26] ----
  const float* sb = seq + (size_t)b * (LL * TT);
  for (int i = tid; i < LL * TT; i += 1024) att[i] = sb[i];
  __syncthreads();   // B0

  // ---- phase 1: interp sums + bitmasks (threads 0..127) ----
  if (tid < 128) {
    int w = tid;
    int k = w >> 1;
    int i0, i1; float c0, c1;
    if ((w & 1) == 0) {
      if (k == 0) { i0 = 0; i1 = 0; c0 = 1.f; c1 = 0.f; }
      else        { i0 = k - 1; i1 = k; c0 = 0.25f; c1 = 0.75f; }
    } else {
      if (k == 63) { i0 = 63; i1 = 63; c0 = 1.f; c1 = 0.f; }
      else         { i0 = k; i1 = k + 1; c0 = 0.75f; c1 = 0.25f; }
    }
    float S = 0.f, S2 = 0.f, A = 0.f;
    for (int t = 0; t < n; ++t) {
      float v = c0 * att[i0 * TT + t] + c1 * att[i1 * TT + t];
      float s = v * v;
      S += s; S2 += s * s;
      A += 1.f / (1.f + __expf(-70.f * (v - 0.1f)));
    }
    wsA_lds[w] = A;
    float c = S * S - S2;
    c = wave_sum(c);
    if (lane == 0) wpart[wv] = c;
  }
  if (tid < 64) {
    int x = tid;                       // middle: identity resize, 64 cols
    for (int t = 0; t < TT; ++t) {
      bool pred = (t < n) && (att[x * TT + t] > alpha);
      ull m = __ballot(pred);
      if (x == 0) s_bits[t] = m;
    }
  } else if (tid < 128) {
    int x = tid - 64;                  // low: pairwise mean, 32 cols
    for (int t = 0; t < TT; ++t) {
      bool pred = (x < 32) && (t < n) &&
                  (0.5f * (att[(2 * x) * TT + t] + att[(2 * x + 1) * TT + t]) > alpha);
      ull m = __ballot(pred);
      if (x == 0) s_alow[t] = (unsigned)m;
    }
  }
  __syncthreads();   // B1
  if (tid == 0) irr_part[b] = 0.5f * (wpart[0] + wpart[1]) / (float)n;

  // ---- column bitmasks (t-bits per column) ----
  if (tid < 64) {
    unsigned cb = 0;
#pragma unroll
    for (int t = 0; t < TT; ++t) cb |= (unsigned)((s_bits[t] >> tid) & 1ULL) << t;
    s_cols_mid[tid] = cb;
  } else if (tid < 96) {
    int xc = tid - 64;
    unsigned cb = 0;
#pragma unroll
    for (int t = 0; t < TT; ++t) cb |= ((s_alow[t] >> xc) & 1u) << t;
    s_cols_low[xc] = cb;
  }

  // ---- phase 2: seg CE + correct CE + fore mask (all threads, 4 px each) ----
  {
    const float* mb = masks + (size_t)b * 4096;
    const float* fb = bf + (size_t)b * 8192;
    float A = wsA_lds[tid & 127];
    float cs = fminf(fmaxf(A, 0.f), 1.f);
    float ce_fore = log1pf(__expf(1.f - 2.f * cs));
    float seg_acc = 0.f, cor_acc = 0.f;
    for (int k = 0; k < 4; ++k) {
      int px = k * 1024 + tid;
      float m = mb[px];
      float b0 = fb[px];
      float b1 = fb[4096 + px];
      float mx = fmaxf(b0, b1);
      float e0 = __expf(b0 - mx), e1 = __expf(b1 - mx);
      float inv = 1.f / (e0 + e1);
      float p0 = e0 * inv, p1 = e1 * inv;
      float pm = fmaxf(p0, p1);
      float lse = pm + log1pf(__expf(-fabsf(p1 - p0)));
      seg_acc += lse - ((m > 0.5f) ? p1 : p0);
      bool fore = b1 > b0;
      cor_acc += fore ? ce_fore : 0.313261687518222834f;
      ull fbm = __ballot(fore);
      if (lane == 0) fmsk_lds[k * 16 + wv] = fbm;
    }
    seg_acc = wave_red63(seg_acc);
    cor_acc = wave_red63(cor_acc);
    if (lane == 63) { ps[wv] = seg_acc; pc[wv] = cor_acc; }
  }
  __syncthreads();   // B2
  if (tid == 0) {
    float s = 0.f, c = 0.f;
#pragma unroll
    for (int i = 0; i < 16; ++i) { s += ps[i]; c += pc[i]; }
    seg_part[b] = s;
    cor_part[b] = c;
  }

  // ---- mid branch: 1024 px, 1 px/thread; wave == row y ----
  {
    int y = wv;                  // 0..15
    int x = tid & 63;
    int word = x >> 5;
    int p = (x & 31) * 2;
    ull r0 = fmsk_lds[4 * y + word];
    ull r1 = fmsk_lds[4 * y + 2 + word];
    int cnt = (int)((r0 >> p) & 1) + (int)((r0 >> (p + 1)) & 1)
            + (int)((r1 >> p) & 1) + (int)((r1 >> (p + 1)) & 1);
    bool fm = cnt >= 2;
    unsigned cbk = s_cols_mid[x];
    int lab = (fm && cbk) ? __ffs((int)cbk) : 0;
    if (!fm) cbk = 0;
    ull bmv = __ballot(fm);
    if (lane == 0) s_fmrow[wv] = bmv;

    const float* base = cm + (size_t)b * 27 * 1024 + tid;
    float v[27];
    float xl = 0.f, s0 = 0.f;
#pragma unroll
    for (int c = 0; c < 27; ++c) {
      float r = base[(size_t)c * 1024];
      xl = (c == lab) ? r : xl;
      r = __expf(r);
      v[c] = r;
      s0 += r;
    }
    float inv0 = 1.f / s0;
    float ce_part = __logf(s0) - xl;

    float* os = out_smid + (size_t)b * 26 * 1024 + tid;
#pragma unroll
    for (int t = 0; t < TT; ++t) {
      float m1 = v[t + 1] * inv0;
      os[(size_t)t * 1024] = m1;
      float ri = wave_red63(((cbk >> t) & 1) ? m1 : 0.f);
      float rm = wave_red63(m1);
      if (lane == 63) { s_red_in[wv][t] = ri; s_red_m1[wv][t] = rm; }
    }
    float rce = wave_red63(ce_part);
    if (lane == 63) s_ce[wv] = rce;
  }
  __syncthreads();   // B3
  if (tid < TT) {
    float m2v = 0.f;
#pragma unroll
    for (int r = 0; r < 16; ++r) m2v += (float)__popcll(s_fmrow[r] & s_bits[tid]);
    float si = 0.f, sm = 0.f;
#pragma unroll
    for (int w = 0; w < 16; ++w) { si += s_red_in[w][tid]; sm += s_red_m1[w][tid]; }
    int o = b * TT + tid;
    m2s_mid[o] = m2v;
    inter_mid[o] = si;
    m1s_mid[o] = sm;
  }
  if (tid == TT) {
    float c16 = 0.f;
#pragma unroll
    for (int w = 0; w < 16; ++w) c16 += s_ce[w];
    celm_part[b] = c16;
  }
  __syncthreads();   // B4 (protect s_red/s_ce reuse)

  // ---- low branch: 256 px, threads 0..255 ----
  if (tid < 256) {
    int px = tid;
    int y = px >> 5, x = px & 31;
    int wb = 4 * x + 1;
    int word = wb >> 6;
    int p = wb & 63;
    ull r0 = fmsk_lds[(4 * y + 1) * 2 + word];
    ull r1 = fmsk_lds[(4 * y + 2) * 2 + word];
    int cnt = (int)((r0 >> p) & 1) + (int)((r0 >> (p + 1)) & 1)
            + (int)((r1 >> p) & 1) + (int)((r1 >> (p + 1)) & 1);
    bool fm = cnt >= 2;
    unsigned cbk = s_cols_low[x];
    int lab = (fm && cbk) ? __ffs((int)cbk) : 0;
    if (!fm) cbk = 0;
    ull bmv = __ballot(fm);
    if (lane == 0) {
      fmrow32[2 * wv] = (unsigned)bmv;
      fmrow32[2 * wv + 1] = (unsigned)(bmv >> 32);
    }

    const float* base = cl + (size_t)b * 27 * 256 + px;
    float v[27];
    float xl = 0.f, s0 = 0.f;
#pragma unroll
    for (int c = 0; c < 27; ++c) {
      float r = base[(size_t)c * 256];
      xl = (c == lab) ? r : xl;
      r = __expf(r);
      v[c] = r;
      s0 += r;
    }
    float inv0 = 1.f / s0;
    float ce_part = __logf(s0) - xl;

    float* om  = out_mask + (size_t)b * 27 * 256 + px;
    float* osf = out_slow + (size_t)b * 26 * 256 + px;
    om[0] = fm ? 0.f : 1.f;
#pragma unroll
    for (int t = 0; t < TT; ++t) {
      float m1 = v[t + 1] * inv0;
      osf[(size_t)t * 256] = m1;
      bool m2 = (cbk >> t) & 1;
      om[(size_t)(t + 1) * 256] = m2 ? 1.f : 0.f;
      float ri = wave_red63(m2 ? m1 : 0.f);
      float rm = wave_red63(m1);
      if (lane == 63) { s_red_in[wv][t] = ri; s_red_m1[wv][t] = rm; }
    }
    float rce = wave_red63(ce_part);
    if (lane == 63) s_ce[wv] = rce;
  }
  __syncthreads();   // B5
  if (tid < TT) {
    float m2v = 0.f;
#pragma unroll
    for (int yy = 0; yy < 8; ++yy) m2v += (float)__popc(fmrow32[yy] & s_alow[tid]);
    float si = 0.f, sm = 0.f;
#pragma unroll
    for (int w = 0; w < 4; ++w) { si += s_red_in[w][tid]; sm += s_red_m1[w][tid]; }
    int o = b * TT + tid;
    m2s_low[o] = m2v;
    inter_low[o] = si;
    m1s_low[o] = sm;
  }
  if (tid == TT) cell_part[b] = s_ce[0] + s_ce[1] + s_ce[2] + s_ce[3];
}

// ---------------- finalize scalars ----------------
__global__ __launch_bounds__(1024) void k_final(
    const float* __restrict__ seg_part, const float* __restrict__ cor_part,
    const float* __restrict__ irr_part, const float* __restrict__ celm_part,
    const float* __restrict__ cell_part,
    const float* __restrict__ inter_mid, const float* __restrict__ m1s_mid,
    const float* __restrict__ m2s_mid,
    const float* __restrict__ inter_low, const float* __restrict__ m1s_low,
    const float* __restrict__ m2s_low,
    const int* __restrict__ length, const int* __restrict__ iter_p,
    float* __restrict__ out)
{
  int tid = threadIdx.x;
  float dm = 0.f, dl = 0.f;
  for (int i = tid; i < NB * TT; i += 1024) {
    int b = i / TT, t = i - b * TT;
    int n = length[b] - 1;
    if (t < n) {
      float inv_n = 1.f / (float)n;
      dm += (1.f - (2.f * inter_mid[i] + 1.f) / (m1s_mid[i] + m2s_mid[i] + 1.f)) * inv_n;
      dl += (1.f - (2.f * inter_low[i] + 1.f) / (m1s_low[i] + m2s_low[i] + 1.f)) * inv_n;
    }
  }
  float ss = 0.f, sel = 0.f, ssel = 0.f;
  float irr = 0.f, cell = 0.f, celm = 0.f, cor = 0.f;
  for (int b = tid; b < NB; b += 1024) {
    float v = seg_part[b];
    ss += v;
    float val = v * (1.f / 4096.f);
    if (val < 1.f) { sel += 1.f; ssel += val; }
    irr += irr_part[b]; cell += cell_part[b]; celm += celm_part[b]; cor += cor_part[b];
  }

  dm = wave_sum(dm); dl = wave_sum(dl); ss = wave_sum(ss);
  sel = wave_sum(sel); ssel = wave_sum(ssel);
  irr = wave_sum(irr); celm = wave_sum(celm); cell = wave_sum(cell);
  cor = wave_sum(cor);
  __shared__ float red[9][16];
  int wv = tid >> 6;
  if ((tid & 63) == 0) {
    red[0][wv] = dm; red[1][wv] = dl; red[2][wv] = ss; red[3][wv] = sel;
    red[4][wv] = ssel; red[5][wv] = irr; red[6][wv] = celm; red[7][wv] = cell;
    red[8][wv] = cor;
  }
  __syncthreads();
  if (tid == 0) {
    float a[9];
#pragma unroll
    for (int j = 0; j < 9; ++j) {
      float s = 0.f;
      for (int i = 0; i < 16; ++i) s += red[j][i];
      a[j] = s;
    }
    float pred = (iter_p[0] > 20000) ? (a[4] / fmaxf(a[3], 1.f)) : (a[2] / 2097152.f);
    out[0] = pred;
    out[1] = a[8] / 2097152.f + a[5];
    out[2] = a[7] / 131072.f + a[1] / 512.f;   // loss_low
    out[3] = a[6] / 524288.f + a[0] / 512.f;   // loss_middle
  }
}

extern "C" void kernel_launch(void* const* d_in, const int* in_sizes, int n_in,
                              void* d_out, int out_size, void* d_ws, size_t ws_size,
                              hipStream_t stream) {
  (void)in_sizes; (void)n_in; (void)out_size; (void)ws_size;
  const float* masks  = (const float*)d_in[0];
  const float* bf     = (const float*)d_in[1];
  const float* seq    = (const float*)d_in[2];
  const float* cmid   = (const float*)d_in[3];
  const float* clow   = (const float*)d_in[4];
  const int*   length = (const int*)d_in[5];
  const int*   iter   = (const int*)d_in[6];
  const float* alpha  = (const float*)d_in[7];
  float* out = (float*)d_out;

  char* ws = (char*)d_ws;
  // all scratch fully rewritten every launch -> no memset
  float* seg_part  = (float*)(ws + 0);        // 512 f32
  float* cor_part  = (float*)(ws + 2048);     // 512
  float* irr_part  = (float*)(ws + 4096);     // 512
  float* celm_part = (float*)(ws + 6144);     // 512
  float* cell_part = (float*)(ws + 8192);     // 512
  float* inter_mid = (float*)(ws + 10240);    // 13312 f32 each
  float* m1s_mid   = (float*)(ws + 63488);
  float* m2s_mid   = (float*)(ws + 116736);
  float* inter_low = (float*)(ws + 169984);
  float* m1s_low   = (float*)(ws + 223232);
  float* m2s_low   = (float*)(ws + 276480);   // ends 329728

  float* out_mask = out + 4;
  float* out_smid = out + 4 + 3538944;
  float* out_slow = out + 4 + 3538944 + 13631488;

  k_mega<<<NB, 1024, 0, stream>>>(masks, bf, seq, cmid, clow, length, alpha,
                                  out_mask, out_smid, out_slow,
                                  seg_part, cor_part, irr_part, celm_part, cell_part,
                                  inter_mid, m1s_mid, m2s_mid,
                                  inter_low, m1s_low, m2s_low);
  k_final<<<1, 1024, 0, stream>>>(seg_part, cor_part, irr_part, celm_part, cell_part,
                                  inter_mid, m1s_mid, m2s_mid,
                                  inter_low, m1s_low, m2s_low, length, iter, out);
}